// Round 9
// baseline (164.720 us; speedup 1.0000x reference)
//
#include <hip/hip_runtime.h>
#include <math.h>

#define FH 384
#define FW 384
#define DH 96
#define DW 96
#define NIMG 6   // 0,1: pred b0,b1; 2,3: I[:,0] b0,b1; 4,5: I[:,1] b0,b1
#define PLANE (DH * DW)
#define NPIX (2 * PLANE)

// Keys cubic kernel, a = -0.5 (matches jax.image "cubic")
__device__ __forceinline__ float keysc(float x) {
    if (x < 1.f) return ((1.5f * x - 2.5f) * x) * x + 1.f;
    if (x < 2.f) return ((-0.5f * x + 2.5f) * x - 4.f) * x + 2.f;
    return 0.f;
}

// reflect-101 (jnp.pad mode='reflect'), valid for i in [-(n-1), 2n-2]
__device__ __forceinline__ int refl(int i, int n) {
    if (i < 0) i = -i;
    if (i >= n) i = 2 * (n - 1) - i;
    return i;
}

// ---------------- K1: grayscale for 6 images -------------------------------
__global__ void k_gray(const float* __restrict__ pred, const float* __restrict__ I,
                       float* __restrict__ gray) {
    int idx = blockIdx.x * 256 + threadIdx.x;
    const int total = NIMG * FH * FW;
    if (idx >= total) return;
    int img = idx / (FH * FW);
    int px  = idx % (FH * FW);
    const float* src;
    if (img < 2) {
        src = pred + img * 3 * FH * FW;
    } else {
        int j = (img - 2) >> 1, b = (img - 2) & 1;
        src = I + ((b * 2 + j) * 3) * FH * FW;
    }
    float r = src[px], g = src[FH * FW + px], b = src[2 * FH * FW + px];
    gray[idx] = (0.299f * r + 0.587f * g + 0.114f * b) * 255.0f;
}

// ---------------- K2: census + downsample along H (per-channel threads) ----
__global__ void k_census_downH(const float* __restrict__ gray, float* __restrict__ CH) {
    int idx = blockIdx.x * 256 + threadIdx.x;
    const int total = NIMG * 9 * DH * FW;
    if (idx >= total) return;
    int x  = idx % FW;
    int t1 = idx / FW;
    int yo = t1 % DH;
    int t2 = t1 / DH;
    int k  = t2 % 9;
    int img = t2 / 9;
    int dy = k / 3 - 1, dx = k % 3 - 1;
    const float* g = gray + img * FH * FW;
    float acc = 0.f, z = 0.f;
#pragma unroll
    for (int t = 0; t < 16; ++t) {
        int r = 4 * yo - 6 + t;
        if (r < 0 || r >= FH) continue;
        float w = keysc(fabsf((float)t - 7.5f) * 0.25f);
        z += w;
        float gc = g[r * FW + x];
        int r2 = r + dy, c2 = x + dx;
        float gn = (r2 < 0 || r2 >= FH || c2 < 0 || c2 >= FW) ? 0.f : g[r2 * FW + c2];
        float tt = gn - gc;
        acc += w * (tt / sqrtf(0.81f + tt * tt));
    }
    CH[idx] = acc / z;
}

// ---------------- K3: generic downsample along W ---------------------------
__global__ void k_downW(const float* __restrict__ src, float* __restrict__ dst, int nrows) {
    int idx = blockIdx.x * 256 + threadIdx.x;
    int total = nrows * DW;
    if (idx >= total) return;
    int xo = idx % DW;
    int row = idx / DW;
    const float* s = src + row * FW;
    float acc = 0.f, z = 0.f;
#pragma unroll
    for (int t = 0; t < 16; ++t) {
        int i = 4 * xo - 6 + t;
        if (i < 0 || i >= FW) continue;
        float w = keysc(fabsf((float)t - 7.5f) * 0.25f);
        z += w;
        acc += w * s[i];
    }
    dst[idx] = acc / z;
}

// ---------------- K4: raw channels downsample along H ----------------------
__global__ void k_raw_downH(const float* __restrict__ pred, const float* __restrict__ I,
                            float* __restrict__ RH) {
    int idx = blockIdx.x * 256 + threadIdx.x;
    const int total = NIMG * 3 * DH * FW;
    if (idx >= total) return;
    int x  = idx % FW;
    int t1 = idx / FW;
    int yo = t1 % DH;
    int t2 = t1 / DH;
    int c  = t2 % 3;
    int img = t2 / 3;
    const float* src;
    if (img < 2) {
        src = pred + (img * 3 + c) * FH * FW;
    } else {
        int j = (img - 2) >> 1, b = (img - 2) & 1;
        src = I + (((b * 2 + j) * 3) + c) * FH * FW;
    }
    float acc = 0.f, z = 0.f;
#pragma unroll
    for (int t = 0; t < 16; ++t) {
        int r = 4 * yo - 6 + t;
        if (r < 0 || r >= FH) continue;
        float w = keysc(fabsf((float)t - 7.5f) * 0.25f);
        z += w;
        acc += w * src[r * FW + x];
    }
    RH[idx] = acc / z;
}

// ---------------- K5: n2 per (neighbor image, position) --------------------
__global__ void k_n2(const float* __restrict__ CD, float* __restrict__ N2) {
    int idx = blockIdx.x * 256 + threadIdx.x;
    if (idx >= 4 * PLANE) return;
    int img4 = idx / PLANE;
    int pos  = idx % PLANE;
    int y = pos / DW, x = pos % DW;
    int ry[3], rx[3];
#pragma unroll
    for (int kk = 0; kk < 3; ++kk) {
        ry[kk] = refl(y + kk - 1, DH);
        rx[kk] = refl(x + kk - 1, DW);
    }
    const float* C = CD + (2 + img4) * 9 * PLANE;
    float s = 0.f;
#pragma unroll
    for (int c = 0; c < 9; ++c)
#pragma unroll
        for (int ky = 0; ky < 3; ++ky)
#pragma unroll
            for (int kx = 0; kx < 3; ++kx) {
                float v = C[c * PLANE + ry[ky] * DW + rx[kx]];
                s += v * v;
            }
    N2[idx] = s;
}

// ---------------- K6: matching, thread=(pixel,j,dy), global-coalesced ------
__global__ __launch_bounds__(256) void k_match_int(const float* __restrict__ CD,
                                                   const float* __restrict__ N2,
                                                   float* __restrict__ bestd,
                                                   int* __restrict__ bestn) {
    int bid  = blockIdx.x;
    int g    = bid / 72;               // 0..13 -> (j, dy)
    int tile = bid % 72;
    int pid  = tile * 256 + threadIdx.x;   // 0..18431
    int j  = g / 7;
    int dy = g % 7 - 3;
    int b   = pid / PLANE;
    int pos = pid % PLANE;
    int y = pos / DW, x = pos % DW;

    int yy = refl(y + dy, DH);
    int r0 = refl(yy - 1, DH), r1 = yy, r2 = refl(yy + 1, DH);
    int pr0 = refl(y - 1, DH), pr2 = refl(y + 1, DH);
    int xb = min(max(x - 4, 0), DW - 9);   // 9-col window base (exact for x in [4,91])
    int xp = min(max(x - 1, 0), DW - 3);   // p 3-col base (exact for interior)

    const float* Cp  = CD + (b * 9) * PLANE;
    const float* Cn  = CD + ((2 + 2 * j + b) * 9) * PLANE;
    const float* N2p = N2 + (2 * j + b) * PLANE;

    float dot[7];
#pragma unroll
    for (int i = 0; i < 7; ++i) dot[i] = 0.f;

#pragma unroll
    for (int c = 0; c < 9; ++c) {
        const float* pc = Cp + c * PLANE;
        const float* nc = Cn + c * PLANE;
        float p0[3], p1[3], p2[3];
#pragma unroll
        for (int kx = 0; kx < 3; ++kx) {
            p0[kx] = pc[pr0 * DW + xp + kx];
            p1[kx] = pc[y   * DW + xp + kx];
            p2[kx] = pc[pr2 * DW + xp + kx];
        }
        float w0[9], w1[9], w2[9];
#pragma unroll
        for (int i = 0; i < 9; ++i) {
            w0[i] = nc[r0 * DW + xb + i];
            w1[i] = nc[r1 * DW + xb + i];
            w2[i] = nc[r2 * DW + xb + i];
        }
#pragma unroll
        for (int dx = 0; dx < 7; ++dx) {
            float d = dot[dx];
            d += p0[0] * w0[dx + 0]; d += p0[1] * w0[dx + 1]; d += p0[2] * w0[dx + 2];
            d += p1[0] * w1[dx + 0]; d += p1[1] * w1[dx + 1]; d += p1[2] * w1[dx + 2];
            d += p2[0] * w2[dx + 0]; d += p2[1] * w2[dx + 1]; d += p2[2] * w2[dx + 2];
            dot[dx] = d;
        }
    }

    float best = INFINITY;
    int bn = 1 << 30;
    int nbase = j * 49 + (dy + 3) * 7;
#pragma unroll
    for (int dx = 0; dx < 7; ++dx) {
        int xxc = min(max(x + dx - 3, 0), DW - 1);   // == refl(x+dx) for interior x
        float dis = N2p[yy * DW + xxc] - 2.f * dot[dx];
        if (dis < best) { best = dis; bn = nbase + dx; }   // dx ascending
    }
    bestd[g * NPIX + pid] = best;
    bestn[g * NPIX + pid] = bn;
}

// ---------------- K6b: exact scalar recompute for x-edge pixels ------------
__global__ void k_match_edge(const float* __restrict__ CD, const float* __restrict__ N2,
                             float* __restrict__ bestd, int* __restrict__ bestn) {
    int t = blockIdx.x * 256 + threadIdx.x;
    if (t >= 14 * 1536) return;
    int g  = t / 1536;
    int pe = t % 1536;
    int j = g / 7, dy = g % 7 - 3;
    int b   = pe / 768;
    int rem = pe % 768;
    int y  = rem / 8;
    int xi = rem % 8;
    int x  = (xi < 4) ? xi : 88 + xi;
    int pid = b * PLANE + y * DW + x;

    int yy = refl(y + dy, DH);
    int pry[3], prx[3], nry[3];
#pragma unroll
    for (int kk = 0; kk < 3; ++kk) {
        pry[kk] = refl(y + kk - 1, DH);
        prx[kk] = refl(x + kk - 1, DW);
        nry[kk] = refl(yy + kk - 1, DH);
    }
    int xx7[7], nrx7[7][3];
#pragma unroll
    for (int dx = 0; dx < 7; ++dx) {
        xx7[dx] = refl(x + dx - 3, DW);
#pragma unroll
        for (int kk = 0; kk < 3; ++kk) nrx7[dx][kk] = refl(xx7[dx] + kk - 1, DW);
    }

    const float* Cp = CD + (b * 9) * PLANE;
    const float* Cn = CD + ((2 + 2 * j + b) * 9) * PLANE;

    float dot[7];
#pragma unroll
    for (int i = 0; i < 7; ++i) dot[i] = 0.f;

    for (int c = 0; c < 9; ++c) {
        const float* pc = Cp + c * PLANE;
        const float* nc = Cn + c * PLANE;
        float p[3][3];
#pragma unroll
        for (int ky = 0; ky < 3; ++ky)
#pragma unroll
            for (int kx = 0; kx < 3; ++kx)
                p[ky][kx] = pc[pry[ky] * DW + prx[kx]];
#pragma unroll
        for (int dx = 0; dx < 7; ++dx) {
            float d = dot[dx];
#pragma unroll
            for (int ky = 0; ky < 3; ++ky)
#pragma unroll
                for (int kx = 0; kx < 3; ++kx)
                    d += p[ky][kx] * nc[nry[ky] * DW + nrx7[dx][kx]];
            dot[dx] = d;
        }
    }

    const float* N2p = N2 + (2 * j + b) * PLANE;
    float best = INFINITY;
    int bn = 1 << 30;
    int nbase = j * 49 + (dy + 3) * 7;
#pragma unroll
    for (int dx = 0; dx < 7; ++dx) {
        float dis = N2p[yy * DW + xx7[dx]] - 2.f * dot[dx];
        if (dis < best) { best = dis; bn = nbase + dx; }
    }
    bestd[g * NPIX + pid] = best;
    bestn[g * NPIX + pid] = bn;
}

// ---------------- K7: combine 14 groups + loss gather ----------------------
__global__ __launch_bounds__(256) void k_combine(const float* __restrict__ bestd,
                                                 const int* __restrict__ bestn,
                                                 const float* __restrict__ RD,
                                                 float* __restrict__ partial) {
    int pid = blockIdx.x * 256 + threadIdx.x;   // 0..18431
    int b   = pid / PLANE;
    int pos = pid % PLANE;
    int y = pos / DW, x = pos % DW;

    float d0 = bestd[pid];
    int   n0 = bestn[pid];
#pragma unroll
    for (int g = 1; g < 14; ++g) {
        float d = bestd[g * NPIX + pid];
        int   n = bestn[g * NPIX + pid];
        if (d < d0 || (d == d0 && n < n0)) { d0 = d; n0 = n; }
    }

    int j = n0 / 49, rr = n0 % 49;
    int dy = rr / 7 - 3, dx = rr % 7 - 3;
    int yy = refl(y + dy, DH), xx = refl(x + dx, DW);
    int ry0[3], rx0[3], ry[3], rx[3];
#pragma unroll
    for (int kk = 0; kk < 3; ++kk) {
        ry0[kk] = refl(y + kk - 1, DH);
        rx0[kk] = refl(x + kk - 1, DW);
        ry[kk]  = refl(yy + kk - 1, DH);
        rx[kk]  = refl(xx + kk - 1, DW);
    }
    const float* RDp = RD + b * 3 * PLANE;
    const float* RDn = RD + (2 + 2 * j + b) * 3 * PLANE;
    float loss = 0.f;
#pragma unroll
    for (int c = 0; c < 3; ++c)
#pragma unroll
        for (int ky = 0; ky < 3; ++ky)
#pragma unroll
            for (int kx = 0; kx < 3; ++kx) {
                float a = RDp[c * PLANE + ry0[ky] * DW + rx0[kx]];
                float m = RDn[c * PLANE + ry[ky] * DW + rx[kx]];
                float d = a - m;
                loss += d * d;
            }

    __shared__ float red[256];
    red[threadIdx.x] = loss;
    __syncthreads();
#pragma unroll
    for (int s = 128; s > 0; s >>= 1) {
        if (threadIdx.x < s) red[threadIdx.x] += red[threadIdx.x + s];
        __syncthreads();
    }
    if (threadIdx.x == 0) partial[blockIdx.x] = red[0];
}

// ---------------- K8: final reduction --------------------------------------
#define NPART 72
__global__ void k_final(const float* __restrict__ partial, float* __restrict__ out) {
    __shared__ float red[128];
    float v = (threadIdx.x < NPART) ? partial[threadIdx.x] : 0.f;
    red[threadIdx.x] = v;
    __syncthreads();
#pragma unroll
    for (int s = 64; s > 0; s >>= 1) {
        if (threadIdx.x < s) red[threadIdx.x] += red[threadIdx.x + s];
        __syncthreads();
    }
    // mean over [b=2, hw=9216, 27] with the 0.5 factor
    if (threadIdx.x == 0) out[0] = red[0] * (0.5f / 497664.0f);
}

extern "C" void kernel_launch(void* const* d_in, const int* in_sizes, int n_in,
                              void* d_out, int out_size, void* d_ws, size_t ws_size,
                              hipStream_t stream) {
    const float* pred = (const float*)d_in[0];   // [2,3,384,384]
    const float* I    = (const float*)d_in[1];   // [2,2,3,384,384]
    float* out = (float*)d_out;
    float* ws  = (float*)d_ws;

    // workspace layout (floats):
    //   CD   [0, 497664)                 6*9*96*96
    //   RD   [497664, 663552)            6*3*96*96
    //   scratch S = 663552:
    //     gray [S, S+884736)             (dead after census_downH)
    //     CH   [S+884736, S+2875392)     (dead after downW)
    //     RH   [S+2875392, S+3538944)    (dead after downW)
    //   reused after downW:
    //     N2    [S, S+36864)             4*9216
    //     bestd [S+36864, S+294912)      14*18432
    //     bestn [S+294912, S+552960)     14*18432 (int)
    //     part  [S+552960, S+553032)     72
    float* CD   = ws;
    float* RD   = CD + 497664;
    float* S    = RD + 165888;
    float* gray = S;
    float* CH   = S + 884736;
    float* RH   = CH + 1990656;
    float* N2   = S;
    float* bestd = S + 36864;
    int*   bestn = (int*)(S + 294912);
    float* part  = S + 552960;

    k_gray<<<(NIMG * FH * FW + 255) / 256, 256, 0, stream>>>(pred, I, gray);
    k_census_downH<<<(NIMG * 9 * DH * FW + 255) / 256, 256, 0, stream>>>(gray, CH);
    k_raw_downH<<<(NIMG * 3 * DH * FW + 255) / 256, 256, 0, stream>>>(pred, I, RH);
    // one combined W-downsample over CH|RH rows -> CD|RD
    k_downW<<<((NIMG * 12 * DH) * DW + 255) / 256, 256, 0, stream>>>(CH, CD, NIMG * 12 * DH);
    k_n2<<<(4 * PLANE + 255) / 256, 256, 0, stream>>>(CD, N2);
    k_match_int<<<14 * 72, 256, 0, stream>>>(CD, N2, bestd, bestn);
    k_match_edge<<<(14 * 1536 + 255) / 256, 256, 0, stream>>>(CD, N2, bestd, bestn);
    k_combine<<<NPIX / 256, 256, 0, stream>>>(bestd, bestn, RD, part);
    k_final<<<1, 128, 0, stream>>>(part, out);
}

// Round 10
// 118.940 us; speedup vs baseline: 1.3849x; 1.3849x over previous
//
#include <hip/hip_runtime.h>
#include <math.h>

#define FH 384
#define FW 384
#define DH 96
#define DW 96
#define NIMG 6   // 0,1: pred b0,b1; 2,3: I[:,0] b0,b1; 4,5: I[:,1] b0,b1
#define PLANE (DH * DW)
#define NPIX (2 * PLANE)

// Keys cubic kernel, a = -0.5 (matches jax.image "cubic")
__device__ __forceinline__ float keysc(float x) {
    if (x < 1.f) return ((1.5f * x - 2.5f) * x) * x + 1.f;
    if (x < 2.f) return ((-0.5f * x + 2.5f) * x - 4.f) * x + 2.f;
    return 0.f;
}

// reflect-101 (jnp.pad mode='reflect'), valid for i in [-(n-1), 2n-2]
__device__ __forceinline__ int refl(int i, int n) {
    if (i < 0) i = -i;
    if (i >= n) i = 2 * (n - 1) - i;
    return i;
}

// ---------------- K1: grayscale for 6 images -------------------------------
__global__ void k_gray(const float* __restrict__ pred, const float* __restrict__ I,
                       float* __restrict__ gray) {
    int idx = blockIdx.x * 256 + threadIdx.x;
    const int total = NIMG * FH * FW;
    if (idx >= total) return;
    int img = idx / (FH * FW);
    int px  = idx % (FH * FW);
    const float* src;
    if (img < 2) {
        src = pred + img * 3 * FH * FW;
    } else {
        int j = (img - 2) >> 1, b = (img - 2) & 1;
        src = I + ((b * 2 + j) * 3) * FH * FW;
    }
    float r = src[px], g = src[FH * FW + px], b = src[2 * FH * FW + px];
    gray[idx] = (0.299f * r + 0.587f * g + 0.114f * b) * 255.0f;
}

// ---------------- K2: census + downsample along H (per-channel threads) ----
__global__ void k_census_downH(const float* __restrict__ gray, float* __restrict__ CH) {
    int idx = blockIdx.x * 256 + threadIdx.x;
    const int total = NIMG * 9 * DH * FW;
    if (idx >= total) return;
    int x  = idx % FW;
    int t1 = idx / FW;
    int yo = t1 % DH;
    int t2 = t1 / DH;
    int k  = t2 % 9;
    int img = t2 / 9;
    int dy = k / 3 - 1, dx = k % 3 - 1;
    const float* g = gray + img * FH * FW;
    float acc = 0.f, z = 0.f;
#pragma unroll
    for (int t = 0; t < 16; ++t) {
        int r = 4 * yo - 6 + t;
        if (r < 0 || r >= FH) continue;
        float w = keysc(fabsf((float)t - 7.5f) * 0.25f);
        z += w;
        float gc = g[r * FW + x];
        int r2 = r + dy, c2 = x + dx;
        float gn = (r2 < 0 || r2 >= FH || c2 < 0 || c2 >= FW) ? 0.f : g[r2 * FW + c2];
        float tt = gn - gc;
        acc += w * (tt / sqrtf(0.81f + tt * tt));
    }
    CH[idx] = acc / z;
}

// ---------------- K3: generic downsample along W ---------------------------
__global__ void k_downW(const float* __restrict__ src, float* __restrict__ dst, int nrows) {
    int idx = blockIdx.x * 256 + threadIdx.x;
    int total = nrows * DW;
    if (idx >= total) return;
    int xo = idx % DW;
    int row = idx / DW;
    const float* s = src + row * FW;
    float acc = 0.f, z = 0.f;
#pragma unroll
    for (int t = 0; t < 16; ++t) {
        int i = 4 * xo - 6 + t;
        if (i < 0 || i >= FW) continue;
        float w = keysc(fabsf((float)t - 7.5f) * 0.25f);
        z += w;
        acc += w * s[i];
    }
    dst[idx] = acc / z;
}

// ---------------- K4: raw channels downsample along H ----------------------
__global__ void k_raw_downH(const float* __restrict__ pred, const float* __restrict__ I,
                            float* __restrict__ RH) {
    int idx = blockIdx.x * 256 + threadIdx.x;
    const int total = NIMG * 3 * DH * FW;
    if (idx >= total) return;
    int x  = idx % FW;
    int t1 = idx / FW;
    int yo = t1 % DH;
    int t2 = t1 / DH;
    int c  = t2 % 3;
    int img = t2 / 3;
    const float* src;
    if (img < 2) {
        src = pred + (img * 3 + c) * FH * FW;
    } else {
        int j = (img - 2) >> 1, b = (img - 2) & 1;
        src = I + (((b * 2 + j) * 3) + c) * FH * FW;
    }
    float acc = 0.f, z = 0.f;
#pragma unroll
    for (int t = 0; t < 16; ++t) {
        int r = 4 * yo - 6 + t;
        if (r < 0 || r >= FH) continue;
        float w = keysc(fabsf((float)t - 7.5f) * 0.25f);
        z += w;
        acc += w * src[r * FW + x];
    }
    RH[idx] = acc / z;
}

// ---------------- K5: n2 per (neighbor image, position) --------------------
__global__ void k_n2(const float* __restrict__ CD, float* __restrict__ N2) {
    int idx = blockIdx.x * 256 + threadIdx.x;
    if (idx >= 4 * PLANE) return;
    int img4 = idx / PLANE;
    int pos  = idx % PLANE;
    int y = pos / DW, x = pos % DW;
    int ry[3], rx[3];
#pragma unroll
    for (int kk = 0; kk < 3; ++kk) {
        ry[kk] = refl(y + kk - 1, DH);
        rx[kk] = refl(x + kk - 1, DW);
    }
    const float* C = CD + (2 + img4) * 9 * PLANE;
    float s = 0.f;
#pragma unroll
    for (int c = 0; c < 9; ++c)
#pragma unroll
        for (int ky = 0; ky < 3; ++ky)
#pragma unroll
            for (int kx = 0; kx < 3; ++kx) {
                float v = C[c * PLANE + ry[ky] * DW + rx[kx]];
                s += v * v;
            }
    N2[idx] = s;
}

// ---------------- K6: matching, thread=(pixel,j,dy), global-coalesced ------
__global__ __launch_bounds__(256) void k_match_int(const float* __restrict__ CD,
                                                   const float* __restrict__ N2,
                                                   float* __restrict__ bestd,
                                                   int* __restrict__ bestn) {
    int bid  = blockIdx.x;
    int g    = bid / 72;               // 0..13 -> (j, dy)
    int tile = bid % 72;
    int pid  = tile * 256 + threadIdx.x;   // 0..18431
    int j  = g / 7;
    int dy = g % 7 - 3;
    int b   = pid / PLANE;
    int pos = pid % PLANE;
    int y = pos / DW, x = pos % DW;

    int yy = refl(y + dy, DH);
    int r0 = refl(yy - 1, DH), r1 = yy, r2 = refl(yy + 1, DH);
    int pr0 = refl(y - 1, DH), pr2 = refl(y + 1, DH);
    int xb = min(max(x - 4, 0), DW - 9);   // 9-col window base (exact for x in [4,91])
    int xp = min(max(x - 1, 0), DW - 3);   // p 3-col base (exact for interior)

    const float* Cp  = CD + (b * 9) * PLANE;
    const float* Cn  = CD + ((2 + 2 * j + b) * 9) * PLANE;
    const float* N2p = N2 + (2 * j + b) * PLANE;

    float dot[7];
#pragma unroll
    for (int i = 0; i < 7; ++i) dot[i] = 0.f;

#pragma unroll
    for (int c = 0; c < 9; ++c) {
        const float* pc = Cp + c * PLANE;
        const float* nc = Cn + c * PLANE;
        float p0[3], p1[3], p2[3];
#pragma unroll
        for (int kx = 0; kx < 3; ++kx) {
            p0[kx] = pc[pr0 * DW + xp + kx];
            p1[kx] = pc[y   * DW + xp + kx];
            p2[kx] = pc[pr2 * DW + xp + kx];
        }
        float w0[9], w1[9], w2[9];
#pragma unroll
        for (int i = 0; i < 9; ++i) {
            w0[i] = nc[r0 * DW + xb + i];
            w1[i] = nc[r1 * DW + xb + i];
            w2[i] = nc[r2 * DW + xb + i];
        }
#pragma unroll
        for (int dx = 0; dx < 7; ++dx) {
            float d = dot[dx];
            d += p0[0] * w0[dx + 0]; d += p0[1] * w0[dx + 1]; d += p0[2] * w0[dx + 2];
            d += p1[0] * w1[dx + 0]; d += p1[1] * w1[dx + 1]; d += p1[2] * w1[dx + 2];
            d += p2[0] * w2[dx + 0]; d += p2[1] * w2[dx + 1]; d += p2[2] * w2[dx + 2];
            dot[dx] = d;
        }
    }

    float best = INFINITY;
    int bn = 1 << 30;
    int nbase = j * 49 + (dy + 3) * 7;
#pragma unroll
    for (int dx = 0; dx < 7; ++dx) {
        int xxc = min(max(x + dx - 3, 0), DW - 1);   // == refl(x+dx) for interior x
        float dis = N2p[yy * DW + xxc] - 2.f * dot[dx];
        if (dis < best) { best = dis; bn = nbase + dx; }   // dx ascending
    }
    bestd[g * NPIX + pid] = best;
    bestn[g * NPIX + pid] = bn;
}

// ---------------- K6b: wave-parallel exact recompute for x-edge pixels -----
// one wave per (g, pe); lanes l = c*7+dx (l < 63); overwrites edge pids
__global__ __launch_bounds__(256) void k_match_edge(const float* __restrict__ CD,
                                                    const float* __restrict__ N2,
                                                    float* __restrict__ bestd,
                                                    int* __restrict__ bestn) {
    __shared__ float part[4][64];
    __shared__ float disw[4][8];

    int wid  = threadIdx.x >> 6;
    int lane = threadIdx.x & 63;
    int item = blockIdx.x * 4 + wid;     // 0..21503 = g*1536 + pe
    int g  = item / 1536;
    int pe = item % 1536;
    int j = g / 7, dy = g % 7 - 3;
    int b   = pe / 768;
    int rem = pe % 768;
    int y  = rem / 8;
    int xi = rem % 8;
    int x  = (xi < 4) ? xi : 88 + xi;
    int pid = b * PLANE + y * DW + x;
    int yy = refl(y + dy, DH);

    int c = lane / 7, dx = lane % 7;     // valid for lane < 63
    float partial = 0.f;
    if (lane < 63) {
        int xx = refl(x + dx - 3, DW);
        const float* pc = CD + (b * 9 + c) * PLANE;
        const float* nc = CD + ((2 + 2 * j + b) * 9 + c) * PLANE;
#pragma unroll
        for (int ky = 0; ky < 3; ++ky) {
            int pry = refl(y + ky - 1, DH);
            int nry = refl(yy + ky - 1, DH);
#pragma unroll
            for (int kx = 0; kx < 3; ++kx) {
                int prx = refl(x + kx - 1, DW);
                int nrx = refl(xx + kx - 1, DW);
                partial += pc[pry * DW + prx] * nc[nry * DW + nrx];
            }
        }
    }
    part[wid][lane] = partial;
    __syncthreads();

    if (lane < 7) {
        float dot = 0.f;
#pragma unroll
        for (int cc = 0; cc < 9; ++cc) dot += part[wid][cc * 7 + lane];
        int xxl = refl(x + lane - 3, DW);
        disw[wid][lane] = N2[(2 * j + b) * PLANE + yy * DW + xxl] - 2.f * dot;
    }
    __syncthreads();

    if (lane == 0) {
        float best = INFINITY;
        int bn = 1 << 30;
        int nbase = j * 49 + (dy + 3) * 7;
#pragma unroll
        for (int dxx = 0; dxx < 7; ++dxx) {
            float d = disw[wid][dxx];
            if (d < best) { best = d; bn = nbase + dxx; }   // dx ascending
        }
        bestd[g * NPIX + pid] = best;
        bestn[g * NPIX + pid] = bn;
    }
}

// ---------------- K7: combine 14 groups + loss gather ----------------------
__global__ __launch_bounds__(256) void k_combine(const float* __restrict__ bestd,
                                                 const int* __restrict__ bestn,
                                                 const float* __restrict__ RD,
                                                 float* __restrict__ partial) {
    int pid = blockIdx.x * 256 + threadIdx.x;   // 0..18431
    int b   = pid / PLANE;
    int pos = pid % PLANE;
    int y = pos / DW, x = pos % DW;

    float d0 = bestd[pid];
    int   n0 = bestn[pid];
#pragma unroll
    for (int g = 1; g < 14; ++g) {
        float d = bestd[g * NPIX + pid];
        int   n = bestn[g * NPIX + pid];
        if (d < d0 || (d == d0 && n < n0)) { d0 = d; n0 = n; }
    }

    int j = n0 / 49, rr = n0 % 49;
    int dy = rr / 7 - 3, dx = rr % 7 - 3;
    int yy = refl(y + dy, DH), xx = refl(x + dx, DW);
    int ry0[3], rx0[3], ry[3], rx[3];
#pragma unroll
    for (int kk = 0; kk < 3; ++kk) {
        ry0[kk] = refl(y + kk - 1, DH);
        rx0[kk] = refl(x + kk - 1, DW);
        ry[kk]  = refl(yy + kk - 1, DH);
        rx[kk]  = refl(xx + kk - 1, DW);
    }
    const float* RDp = RD + b * 3 * PLANE;
    const float* RDn = RD + (2 + 2 * j + b) * 3 * PLANE;
    float loss = 0.f;
#pragma unroll
    for (int c = 0; c < 3; ++c)
#pragma unroll
        for (int ky = 0; ky < 3; ++ky)
#pragma unroll
            for (int kx = 0; kx < 3; ++kx) {
                float a = RDp[c * PLANE + ry0[ky] * DW + rx0[kx]];
                float m = RDn[c * PLANE + ry[ky] * DW + rx[kx]];
                float d = a - m;
                loss += d * d;
            }

    __shared__ float red[256];
    red[threadIdx.x] = loss;
    __syncthreads();
#pragma unroll
    for (int s = 128; s > 0; s >>= 1) {
        if (threadIdx.x < s) red[threadIdx.x] += red[threadIdx.x + s];
        __syncthreads();
    }
    if (threadIdx.x == 0) partial[blockIdx.x] = red[0];
}

// ---------------- K8: final reduction --------------------------------------
#define NPART 72
__global__ void k_final(const float* __restrict__ partial, float* __restrict__ out) {
    __shared__ float red[128];
    float v = (threadIdx.x < NPART) ? partial[threadIdx.x] : 0.f;
    red[threadIdx.x] = v;
    __syncthreads();
#pragma unroll
    for (int s = 64; s > 0; s >>= 1) {
        if (threadIdx.x < s) red[threadIdx.x] += red[threadIdx.x + s];
        __syncthreads();
    }
    // mean over [b=2, hw=9216, 27] with the 0.5 factor
    if (threadIdx.x == 0) out[0] = red[0] * (0.5f / 497664.0f);
}

extern "C" void kernel_launch(void* const* d_in, const int* in_sizes, int n_in,
                              void* d_out, int out_size, void* d_ws, size_t ws_size,
                              hipStream_t stream) {
    const float* pred = (const float*)d_in[0];   // [2,3,384,384]
    const float* I    = (const float*)d_in[1];   // [2,2,3,384,384]
    float* out = (float*)d_out;
    float* ws  = (float*)d_ws;

    // workspace layout (floats):
    //   CD   [0, 497664)                 6*9*96*96
    //   RD   [497664, 663552)            6*3*96*96
    //   scratch S = 663552:
    //     gray [S, S+884736)             (dead after census_downH)
    //     CH   [S+884736, S+2875392)     (dead after downW)
    //     RH   [S+2875392, S+3538944)    (dead after downW)
    //   reused after downW:
    //     N2    [S, S+36864)             4*9216
    //     bestd [S+36864, S+294912)      14*18432
    //     bestn [S+294912, S+552960)     14*18432 (int)
    //     part  [S+552960, S+553032)     72
    float* CD   = ws;
    float* RD   = CD + 497664;
    float* S    = RD + 165888;
    float* gray = S;
    float* CH   = S + 884736;
    float* RH   = CH + 1990656;
    float* N2   = S;
    float* bestd = S + 36864;
    int*   bestn = (int*)(S + 294912);
    float* part  = S + 552960;

    k_gray<<<(NIMG * FH * FW + 255) / 256, 256, 0, stream>>>(pred, I, gray);
    k_census_downH<<<(NIMG * 9 * DH * FW + 255) / 256, 256, 0, stream>>>(gray, CH);
    k_raw_downH<<<(NIMG * 3 * DH * FW + 255) / 256, 256, 0, stream>>>(pred, I, RH);
    // one combined W-downsample over CH|RH rows -> CD|RD
    k_downW<<<((NIMG * 12 * DH) * DW + 255) / 256, 256, 0, stream>>>(CH, CD, NIMG * 12 * DH);
    k_n2<<<(4 * PLANE + 255) / 256, 256, 0, stream>>>(CD, N2);
    k_match_int<<<14 * 72, 256, 0, stream>>>(CD, N2, bestd, bestn);
    k_match_edge<<<(14 * 1536) / 4 / 64, 256, 0, stream>>>(CD, N2, bestd, bestn);
    k_combine<<<NPIX / 256, 256, 0, stream>>>(bestd, bestn, RD, part);
    k_final<<<1, 128, 0, stream>>>(part, out);
}

// Round 11
// 116.220 us; speedup vs baseline: 1.4173x; 1.0234x over previous
//
#include <hip/hip_runtime.h>
#include <math.h>

#define FH 384
#define FW 384
#define DH 96
#define DW 96
#define NIMG 6   // 0,1: pred b0,b1; 2,3: I[:,0] b0,b1; 4,5: I[:,1] b0,b1
#define PLANE (DH * DW)
#define NPIX (2 * PLANE)

// Keys cubic kernel, a = -0.5 (matches jax.image "cubic")
__device__ __forceinline__ float keysc(float x) {
    if (x < 1.f) return ((1.5f * x - 2.5f) * x) * x + 1.f;
    if (x < 2.f) return ((-0.5f * x + 2.5f) * x - 4.f) * x + 2.f;
    return 0.f;
}

// reflect-101 (jnp.pad mode='reflect'), valid for i in [-(n-1), 2n-2]
__device__ __forceinline__ int refl(int i, int n) {
    if (i < 0) i = -i;
    if (i >= n) i = 2 * (n - 1) - i;
    return i;
}

// ---------------- K1: grayscale for 6 images -------------------------------
__global__ void k_gray(const float* __restrict__ pred, const float* __restrict__ I,
                       float* __restrict__ gray) {
    int idx = blockIdx.x * 256 + threadIdx.x;
    const int total = NIMG * FH * FW;
    if (idx >= total) return;
    int img = idx / (FH * FW);
    int px  = idx % (FH * FW);
    const float* src;
    if (img < 2) {
        src = pred + img * 3 * FH * FW;
    } else {
        int j = (img - 2) >> 1, b = (img - 2) & 1;
        src = I + ((b * 2 + j) * 3) * FH * FW;
    }
    float r = src[px], g = src[FH * FW + px], b = src[2 * FH * FW + px];
    gray[idx] = (0.299f * r + 0.587f * g + 0.114f * b) * 255.0f;
}

// ---------------- K1b: full-res census fields (8 non-center channels) ------
// CF[img][ck][r][x], ck = k<4 ? k : k-1 (channel 4 == center == exactly +0)
__global__ void k_field(const float* __restrict__ gray, float* __restrict__ CF) {
    int idx = blockIdx.x * 256 + threadIdx.x;
    const int total = NIMG * FH * FW;
    if (idx >= total) return;
    int x   = idx % FW;
    int t1  = idx / FW;
    int r   = t1 % FH;
    int img = t1 / FH;
    const float* g = gray + img * FH * FW;
    float gc = g[r * FW + x];
    const int planeF = FH * FW;
    float* out = CF + ((size_t)img * 8) * planeF + r * FW + x;
    int ck = 0;
#pragma unroll
    for (int k = 0; k < 9; ++k) {
        if (k == 4) continue;
        int dy = k / 3 - 1, dx = k % 3 - 1;
        int r2 = r + dy, c2 = x + dx;
        float gn = (r2 < 0 || r2 >= FH || c2 < 0 || c2 >= FW) ? 0.f : g[r2 * FW + c2];
        float tt = gn - gc;   // EXACT softsign expression (keep)
        out[ck * planeF] = tt / sqrtf(0.81f + tt * tt);
        ++ck;
    }
}

// ---------------- K2: H-downsample of census fields (pure load+FMA) --------
// thread = (img, k, yo, x); out CH[img][k][yo][x]; k==4 writes exact 0
__global__ void k_census_downH(const float* __restrict__ CF, float* __restrict__ CH) {
    int idx = blockIdx.x * 256 + threadIdx.x;
    const int total = NIMG * 9 * DH * FW;
    if (idx >= total) return;
    int x  = idx % FW;
    int t1 = idx / FW;
    int yo = t1 % DH;
    int t2 = t1 / DH;
    int k  = t2 % 9;
    int img = t2 / 9;
    if (k == 4) { CH[idx] = 0.f; return; }   // center channel: t - gray == +0
    int ck = (k < 4) ? k : k - 1;
    const float* F = CF + ((size_t)(img * 8 + ck) * FH) * FW + x;
    int rbase = 4 * yo - 6;
    float acc = 0.f, z = 0.f;
    if (rbase >= 0 && rbase + 15 < FH) {
        // fast path: all taps valid; z folds to the same sequential-sum constant
#pragma unroll
        for (int t = 0; t < 16; ++t) {
            float w = keysc(fabsf((float)t - 7.5f) * 0.25f);
            z += w;
            acc += w * F[(rbase + t) * FW];
        }
    } else {
#pragma unroll
        for (int t = 0; t < 16; ++t) {
            int r = rbase + t;
            if (r < 0 || r >= FH) continue;
            float w = keysc(fabsf((float)t - 7.5f) * 0.25f);
            z += w;
            acc += w * F[r * FW];
        }
    }
    CH[idx] = acc / z;
}

// ---------------- K3: generic downsample along W ---------------------------
__global__ void k_downW(const float* __restrict__ src, float* __restrict__ dst, int nrows) {
    int idx = blockIdx.x * 256 + threadIdx.x;
    int total = nrows * DW;
    if (idx >= total) return;
    int xo = idx % DW;
    int row = idx / DW;
    const float* s = src + row * FW;
    float acc = 0.f, z = 0.f;
#pragma unroll
    for (int t = 0; t < 16; ++t) {
        int i = 4 * xo - 6 + t;
        if (i < 0 || i >= FW) continue;
        float w = keysc(fabsf((float)t - 7.5f) * 0.25f);
        z += w;
        acc += w * s[i];
    }
    dst[idx] = acc / z;
}

// ---------------- K4: raw channels downsample along H ----------------------
__global__ void k_raw_downH(const float* __restrict__ pred, const float* __restrict__ I,
                            float* __restrict__ RH) {
    int idx = blockIdx.x * 256 + threadIdx.x;
    const int total = NIMG * 3 * DH * FW;
    if (idx >= total) return;
    int x  = idx % FW;
    int t1 = idx / FW;
    int yo = t1 % DH;
    int t2 = t1 / DH;
    int c  = t2 % 3;
    int img = t2 / 3;
    const float* src;
    if (img < 2) {
        src = pred + (img * 3 + c) * FH * FW;
    } else {
        int j = (img - 2) >> 1, b = (img - 2) & 1;
        src = I + (((b * 2 + j) * 3) + c) * FH * FW;
    }
    float acc = 0.f, z = 0.f;
#pragma unroll
    for (int t = 0; t < 16; ++t) {
        int r = 4 * yo - 6 + t;
        if (r < 0 || r >= FH) continue;
        float w = keysc(fabsf((float)t - 7.5f) * 0.25f);
        z += w;
        acc += w * src[r * FW + x];
    }
    RH[idx] = acc / z;
}

// ---------------- K5: n2 per (neighbor image, position) --------------------
__global__ void k_n2(const float* __restrict__ CD, float* __restrict__ N2) {
    int idx = blockIdx.x * 256 + threadIdx.x;
    if (idx >= 4 * PLANE) return;
    int img4 = idx / PLANE;
    int pos  = idx % PLANE;
    int y = pos / DW, x = pos % DW;
    int ry[3], rx[3];
#pragma unroll
    for (int kk = 0; kk < 3; ++kk) {
        ry[kk] = refl(y + kk - 1, DH);
        rx[kk] = refl(x + kk - 1, DW);
    }
    const float* C = CD + (2 + img4) * 9 * PLANE;
    float s = 0.f;
#pragma unroll
    for (int c = 0; c < 9; ++c)
#pragma unroll
        for (int ky = 0; ky < 3; ++ky)
#pragma unroll
            for (int kx = 0; kx < 3; ++kx) {
                float v = C[c * PLANE + ry[ky] * DW + rx[kx]];
                s += v * v;
            }
    N2[idx] = s;
}

// ---------------- K6: matching, thread=(pixel,j,dy), global-coalesced ------
__global__ __launch_bounds__(256) void k_match_int(const float* __restrict__ CD,
                                                   const float* __restrict__ N2,
                                                   float* __restrict__ bestd,
                                                   int* __restrict__ bestn) {
    int bid  = blockIdx.x;
    int g    = bid / 72;               // 0..13 -> (j, dy)
    int tile = bid % 72;
    int pid  = tile * 256 + threadIdx.x;   // 0..18431
    int j  = g / 7;
    int dy = g % 7 - 3;
    int b   = pid / PLANE;
    int pos = pid % PLANE;
    int y = pos / DW, x = pos % DW;

    int yy = refl(y + dy, DH);
    int r0 = refl(yy - 1, DH), r1 = yy, r2 = refl(yy + 1, DH);
    int pr0 = refl(y - 1, DH), pr2 = refl(y + 1, DH);
    int xb = min(max(x - 4, 0), DW - 9);   // 9-col window base (exact for x in [4,91])
    int xp = min(max(x - 1, 0), DW - 3);   // p 3-col base (exact for interior)

    const float* Cp  = CD + (b * 9) * PLANE;
    const float* Cn  = CD + ((2 + 2 * j + b) * 9) * PLANE;
    const float* N2p = N2 + (2 * j + b) * PLANE;

    float dot[7];
#pragma unroll
    for (int i = 0; i < 7; ++i) dot[i] = 0.f;

#pragma unroll
    for (int c = 0; c < 9; ++c) {
        const float* pc = Cp + c * PLANE;
        const float* nc = Cn + c * PLANE;
        float p0[3], p1[3], p2[3];
#pragma unroll
        for (int kx = 0; kx < 3; ++kx) {
            p0[kx] = pc[pr0 * DW + xp + kx];
            p1[kx] = pc[y   * DW + xp + kx];
            p2[kx] = pc[pr2 * DW + xp + kx];
        }
        float w0[9], w1[9], w2[9];
#pragma unroll
        for (int i = 0; i < 9; ++i) {
            w0[i] = nc[r0 * DW + xb + i];
            w1[i] = nc[r1 * DW + xb + i];
            w2[i] = nc[r2 * DW + xb + i];
        }
#pragma unroll
        for (int dx = 0; dx < 7; ++dx) {
            float d = dot[dx];
            d += p0[0] * w0[dx + 0]; d += p0[1] * w0[dx + 1]; d += p0[2] * w0[dx + 2];
            d += p1[0] * w1[dx + 0]; d += p1[1] * w1[dx + 1]; d += p1[2] * w1[dx + 2];
            d += p2[0] * w2[dx + 0]; d += p2[1] * w2[dx + 1]; d += p2[2] * w2[dx + 2];
            dot[dx] = d;
        }
    }

    float best = INFINITY;
    int bn = 1 << 30;
    int nbase = j * 49 + (dy + 3) * 7;
#pragma unroll
    for (int dx = 0; dx < 7; ++dx) {
        int xxc = min(max(x + dx - 3, 0), DW - 1);   // == refl(x+dx) for interior x
        float dis = N2p[yy * DW + xxc] - 2.f * dot[dx];
        if (dis < best) { best = dis; bn = nbase + dx; }   // dx ascending
    }
    bestd[g * NPIX + pid] = best;
    bestn[g * NPIX + pid] = bn;
}

// ---------------- K6b: wave-parallel exact recompute for x-edge pixels -----
__global__ __launch_bounds__(256) void k_match_edge(const float* __restrict__ CD,
                                                    const float* __restrict__ N2,
                                                    float* __restrict__ bestd,
                                                    int* __restrict__ bestn) {
    __shared__ float part[4][64];
    __shared__ float disw[4][8];

    int wid  = threadIdx.x >> 6;
    int lane = threadIdx.x & 63;
    int item = blockIdx.x * 4 + wid;     // 0..21503 = g*1536 + pe
    int g  = item / 1536;
    int pe = item % 1536;
    int j = g / 7, dy = g % 7 - 3;
    int b   = pe / 768;
    int rem = pe % 768;
    int y  = rem / 8;
    int xi = rem % 8;
    int x  = (xi < 4) ? xi : 88 + xi;
    int pid = b * PLANE + y * DW + x;
    int yy = refl(y + dy, DH);

    int c = lane / 7, dx = lane % 7;     // valid for lane < 63
    float partial = 0.f;
    if (lane < 63) {
        int xx = refl(x + dx - 3, DW);
        const float* pc = CD + (b * 9 + c) * PLANE;
        const float* nc = CD + ((2 + 2 * j + b) * 9 + c) * PLANE;
#pragma unroll
        for (int ky = 0; ky < 3; ++ky) {
            int pry = refl(y + ky - 1, DH);
            int nry = refl(yy + ky - 1, DH);
#pragma unroll
            for (int kx = 0; kx < 3; ++kx) {
                int prx = refl(x + kx - 1, DW);
                int nrx = refl(xx + kx - 1, DW);
                partial += pc[pry * DW + prx] * nc[nry * DW + nrx];
            }
        }
    }
    part[wid][lane] = partial;
    __syncthreads();

    if (lane < 7) {
        float dot = 0.f;
#pragma unroll
        for (int cc = 0; cc < 9; ++cc) dot += part[wid][cc * 7 + lane];
        int xxl = refl(x + lane - 3, DW);
        disw[wid][lane] = N2[(2 * j + b) * PLANE + yy * DW + xxl] - 2.f * dot;
    }
    __syncthreads();

    if (lane == 0) {
        float best = INFINITY;
        int bn = 1 << 30;
        int nbase = j * 49 + (dy + 3) * 7;
#pragma unroll
        for (int dxx = 0; dxx < 7; ++dxx) {
            float d = disw[wid][dxx];
            if (d < best) { best = d; bn = nbase + dxx; }   // dx ascending
        }
        bestd[g * NPIX + pid] = best;
        bestn[g * NPIX + pid] = bn;
    }
}

// ---------------- K7: combine 14 groups + loss gather ----------------------
__global__ __launch_bounds__(256) void k_combine(const float* __restrict__ bestd,
                                                 const int* __restrict__ bestn,
                                                 const float* __restrict__ RD,
                                                 float* __restrict__ partial) {
    int pid = blockIdx.x * 256 + threadIdx.x;   // 0..18431
    int b   = pid / PLANE;
    int pos = pid % PLANE;
    int y = pos / DW, x = pos % DW;

    float d0 = bestd[pid];
    int   n0 = bestn[pid];
#pragma unroll
    for (int g = 1; g < 14; ++g) {
        float d = bestd[g * NPIX + pid];
        int   n = bestn[g * NPIX + pid];
        if (d < d0 || (d == d0 && n < n0)) { d0 = d; n0 = n; }
    }

    int j = n0 / 49, rr = n0 % 49;
    int dy = rr / 7 - 3, dx = rr % 7 - 3;
    int yy = refl(y + dy, DH), xx = refl(x + dx, DW);
    int ry0[3], rx0[3], ry[3], rx[3];
#pragma unroll
    for (int kk = 0; kk < 3; ++kk) {
        ry0[kk] = refl(y + kk - 1, DH);
        rx0[kk] = refl(x + kk - 1, DW);
        ry[kk]  = refl(yy + kk - 1, DH);
        rx[kk]  = refl(xx + kk - 1, DW);
    }
    const float* RDp = RD + b * 3 * PLANE;
    const float* RDn = RD + (2 + 2 * j + b) * 3 * PLANE;
    float loss = 0.f;
#pragma unroll
    for (int c = 0; c < 3; ++c)
#pragma unroll
        for (int ky = 0; ky < 3; ++ky)
#pragma unroll
            for (int kx = 0; kx < 3; ++kx) {
                float a = RDp[c * PLANE + ry0[ky] * DW + rx0[kx]];
                float m = RDn[c * PLANE + ry[ky] * DW + rx[kx]];
                float d = a - m;
                loss += d * d;
            }

    __shared__ float red[256];
    red[threadIdx.x] = loss;
    __syncthreads();
#pragma unroll
    for (int s = 128; s > 0; s >>= 1) {
        if (threadIdx.x < s) red[threadIdx.x] += red[threadIdx.x + s];
        __syncthreads();
    }
    if (threadIdx.x == 0) partial[blockIdx.x] = red[0];
}

// ---------------- K8: final reduction --------------------------------------
#define NPART 72
__global__ void k_final(const float* __restrict__ partial, float* __restrict__ out) {
    __shared__ float red[128];
    float v = (threadIdx.x < NPART) ? partial[threadIdx.x] : 0.f;
    red[threadIdx.x] = v;
    __syncthreads();
#pragma unroll
    for (int s = 64; s > 0; s >>= 1) {
        if (threadIdx.x < s) red[threadIdx.x] += red[threadIdx.x + s];
        __syncthreads();
    }
    // mean over [b=2, hw=9216, 27] with the 0.5 factor
    if (threadIdx.x == 0) out[0] = red[0] * (0.5f / 497664.0f);
}

extern "C" void kernel_launch(void* const* d_in, const int* in_sizes, int n_in,
                              void* d_out, int out_size, void* d_ws, size_t ws_size,
                              hipStream_t stream) {
    const float* pred = (const float*)d_in[0];   // [2,3,384,384]
    const float* I    = (const float*)d_in[1];   // [2,2,3,384,384]
    float* out = (float*)d_out;
    float* ws  = (float*)d_ws;

    // workspace layout (floats):
    //   CD   [0, 497664)                 6*9*96*96
    //   RD   [497664, 663552)            6*3*96*96
    //   scratch S = 663552:
    //     gray [S, S+884736)             (dead after k_field)
    //     CF   [S+884736, S+7962624)     6*8*384*384 (dead after census_downH)
    //     CH   [S+7962624, S+9953280)    6*9*96*384  (dead after downW)
    //     RH   [S+9953280, S+10616832)   6*3*96*384  (dead after downW)
    //   reused after downW (inside dead gray region):
    //     N2    [S, S+36864)             4*9216
    //     bestd [S+36864, S+294912)      14*18432
    //     bestn [S+294912, S+552960)     14*18432 (int)
    //     part  [S+552960, S+553032)     72
    float* CD   = ws;
    float* RD   = CD + 497664;
    float* S    = RD + 165888;
    float* gray = S;
    float* CF   = S + 884736;
    float* CH   = S + 7962624;
    float* RH   = S + 9953280;
    float* N2   = S;
    float* bestd = S + 36864;
    int*   bestn = (int*)(S + 294912);
    float* part  = S + 552960;

    k_gray<<<(NIMG * FH * FW + 255) / 256, 256, 0, stream>>>(pred, I, gray);
    k_field<<<(NIMG * FH * FW + 255) / 256, 256, 0, stream>>>(gray, CF);
    k_census_downH<<<(NIMG * 9 * DH * FW + 255) / 256, 256, 0, stream>>>(CF, CH);
    k_raw_downH<<<(NIMG * 3 * DH * FW + 255) / 256, 256, 0, stream>>>(pred, I, RH);
    // one combined W-downsample over CH|RH rows -> CD|RD
    k_downW<<<((NIMG * 12 * DH) * DW + 255) / 256, 256, 0, stream>>>(CH, CD, NIMG * 12 * DH);
    k_n2<<<(4 * PLANE + 255) / 256, 256, 0, stream>>>(CD, N2);
    k_match_int<<<14 * 72, 256, 0, stream>>>(CD, N2, bestd, bestn);
    k_match_edge<<<(14 * 1536) / 4 / 64, 256, 0, stream>>>(CD, N2, bestd, bestn);
    k_combine<<<NPIX / 256, 256, 0, stream>>>(bestd, bestn, RD, part);
    k_final<<<1, 128, 0, stream>>>(part, out);
}